// Round 18
// baseline (215.174 us; speedup 1.0000x reference)
//
#include <hip/hip_runtime.h>
#include <hip/hip_bf16.h>

// Problem constants (fixed by setup_inputs)
#define E_TOTAL 262144
#define NG      128
#define GRAPHS  64
#define NHEADS  8
#define DKH     64
#define DMODEL  512
#define NNODES  8192

typedef __bf16 bf16x8 __attribute__((ext_vector_type(8)));
typedef float  f32x4  __attribute__((ext_vector_type(4)));
typedef short  s16x4  __attribute__((ext_vector_type(4)));
typedef unsigned short u16x8 __attribute__((ext_vector_type(8)));

typedef __attribute__((address_space(3))) char lds_char;
typedef const __attribute__((address_space(1))) char glb_char;

__device__ inline __hip_bfloat16 f2hbf(float f) { return __float2bfloat16(f); }
__device__ inline unsigned short f2u16(float f) {
    return __builtin_bit_cast(unsigned short, __float2bfloat16(f));
}
__device__ inline __bf16 f2bf(float f) {
    return __builtin_bit_cast(__bf16, f2u16(f));
}
__device__ inline bf16x8 cvt8(float4 lo, float4 hi) {
    bf16x8 o;
    o[0] = f2bf(lo.x); o[1] = f2bf(lo.y); o[2] = f2bf(lo.z); o[3] = f2bf(lo.w);
    o[4] = f2bf(hi.x); o[5] = f2bf(hi.y); o[6] = f2bf(hi.z); o[7] = f2bf(hi.w);
    return o;
}

// ---------------------------------------------------------------------------
// Prep: weight transpose/cast + edge-MLP frag tables (convert-x removed: the
// QKV GEMM now stages A directly from fp32 x with in-register cvt).
// ---------------------------------------------------------------------------
__global__ __launch_bounds__(256) void prep_kernel(
    const float* __restrict__ Wq, const float* __restrict__ Wk,
    const float* __restrict__ Wv, const float* __restrict__ Wo,
    const float* __restrict__ W1, const float* __restrict__ b1,
    const float* __restrict__ W2, const float* __restrict__ b2,
    __hip_bfloat16* __restrict__ wqkvt, __hip_bfloat16* __restrict__ wot,
    __hip_bfloat16* __restrict__ w1fragt, float* __restrict__ b1f,
    __hip_bfloat16* __restrict__ w2at, float* __restrict__ b2f)
{
    int blk = blockIdx.x, tid = threadIdx.x;
    if (blk < 256) {
        __shared__ __align__(16) __hip_bfloat16 tile[64][65];
        const float* src;
        __hip_bfloat16* dstT;
        int n0, k0, nb;
        if (blk < 192) {
            int nt = blk % 24, ktile = blk / 24;
            n0 = nt * 64; k0 = ktile * 64;
            if (n0 < 512)       { src = Wq; nb = n0; }
            else if (n0 < 1024) { src = Wk; nb = n0 - 512; }
            else                { src = Wv; nb = n0 - 1024; }
            dstT = wqkvt;
        } else {
            int t = blk - 192;
            n0 = (t % 8) * 64; k0 = (t / 8) * 64; nb = n0;
            src = Wo; dstT = wot;
        }
        #pragma unroll
        for (int i = 0; i < 16; ++i) {
            int idx = tid + i * 256;
            int kr = idx >> 6, nc = idx & 63;
            tile[kr][nc] = f2hbf(src[(size_t)(k0 + kr) * 512 + nb + nc]);
        }
        __syncthreads();
        #pragma unroll
        for (int i = 0; i < 16; ++i) {
            int idx = tid + i * 256;
            int nr = idx >> 6, kc = idx & 63;
            dstT[(size_t)(n0 + nr) * 512 + k0 + kc] = tile[kc][nr];
        }
    } else {
        __hip_bfloat16 z = f2hbf(0.f);
        // w1fragt: [512][8]
        for (int n = tid; n < 512; n += 256) {
            #pragma unroll
            for (int j = 0; j < 4; ++j) w1fragt[n * 8 + j] = f2hbf(W1[(size_t)j * 512 + n]);
            #pragma unroll
            for (int j = 4; j < 8; ++j) w1fragt[n * 8 + j] = z;
        }
        for (int i = tid; i < 512; i += 256) b1f[i] = b1[i];
        // w2at: [32][64][4], W2 is (512,8) row-major
        for (int i = tid; i < 32 * 64 * 4; i += 256) {
            int t = i >> 8, lane = (i >> 2) & 63, j = i & 3;
            int q = lane >> 4, l = lane & 15;
            w2at[i] = (l < 8) ? f2hbf(W2[(size_t)(16 * t + 4 * q + j) * 8 + l]) : z;
        }
        if (tid < 8) b2f[tid] = b2[tid];
    }
}

// ---------------------------------------------------------------------------
// QKV GEMM body: A = fp32 x, staged via register loads + cvt + ds_write_b128
// (R2-R9-proven deterministic reg-staging protocol); B (bf16 wqkvt) staged
// via global_load_lds w=16 (R10-proven). 128x128 tile, BK=32.
// Epilogue: qkv bf16 (Q,K); V only into vt.
// ---------------------------------------------------------------------------
__device__ __forceinline__ void gemm0_body(
    const float* __restrict__ A, const __hip_bfloat16* __restrict__ BT,
    int row0, int col0,
    const float* __restrict__ bq, const float* __restrict__ bk,
    const float* __restrict__ bv,
    __hip_bfloat16* __restrict__ qkv, __hip_bfloat16* __restrict__ vt,
    __hip_bfloat16* As, __hip_bfloat16* Bs)
{
    const int K = 512;
    int tid = threadIdx.x;
    int lane = tid & 63, quad = lane >> 4, l16 = lane & 15;
    int wave = tid >> 6, wi = wave >> 1, wj = wave & 1;

    f32x4 acc[4][4];
    #pragma unroll
    for (int a = 0; a < 4; a++)
        #pragma unroll
        for (int b = 0; b < 4; b++)
            #pragma unroll
            for (int r = 0; r < 4; r++) acc[a][b][r] = 0.f;

    const float* Ag0 = A + (size_t)(row0 + (tid >> 2)) * K + (tid & 3) * 8;
    const float* Ag1 = Ag0 + (size_t)64 * K;
    const __hip_bfloat16* Bg0 = BT + (size_t)(col0 + (tid >> 2)) * K + (tid & 3) * 8;
    const __hip_bfloat16* Bg1 = Bg0 + (size_t)64 * K;
    char* BsB = (char*)Bs;
    int lidx = tid * 8;

    for (int kt = 0; kt < K / 32; ++kt) {
        // prefetch A (fp32) into registers before the barrier
        float4 a0l = *(const float4*)(Ag0 + kt * 32);
        float4 a0h = *(const float4*)(Ag0 + kt * 32 + 4);
        float4 a1l = *(const float4*)(Ag1 + kt * 32);
        float4 a1h = *(const float4*)(Ag1 + kt * 32 + 4);
        __syncthreads();   // prior iteration's frag reads complete
        __builtin_amdgcn_global_load_lds((glb_char*)(Bg0 + kt * 32), (lds_char*)(BsB + tid * 16), 16, 0, 0);
        __builtin_amdgcn_global_load_lds((glb_char*)(Bg1 + kt * 32), (lds_char*)(BsB + 4096 + tid * 16), 16, 0, 0);
        *(bf16x8*)&As[lidx]        = cvt8(a0l, a0h);
        *(bf16x8*)&As[2048 + lidx] = cvt8(a1l, a1h);
        __syncthreads();   // staging visible (compiler drains vmcnt here)
        bf16x8 af[4], bfr[4];
        #pragma unroll
        for (int t = 0; t < 4; t++)
            af[t] = *(const bf16x8*)&As[(wi * 64 + t * 16 + l16) * 32 + quad * 8];
        #pragma unroll
        for (int t = 0; t < 4; t++)
            bfr[t] = *(const bf16x8*)&Bs[(wj * 64 + t * 16 + l16) * 32 + quad * 8];
        #pragma unroll
        for (int ti = 0; ti < 4; ti++)
            #pragma unroll
            for (int tj = 0; tj < 4; tj++)
                acc[ti][tj] = __builtin_amdgcn_mfma_f32_16x16x32_bf16(af[ti], bfr[tj], acc[ti][tj], 0, 0, 0);
    }

    #pragma unroll
    for (int ti = 0; ti < 4; ti++)
        #pragma unroll
        for (int tj = 0; tj < 4; tj++) {
            int c = col0 + wj * 64 + tj * 16 + l16;
            #pragma unroll
            for (int r = 0; r < 4; r++) {
                int rw = row0 + wi * 64 + ti * 16 + quad * 4 + r;
                float v = acc[ti][tj][r];
                if (c < 1024) {
                    v += (c < 512) ? bq[c] : bk[c - 512];
                    qkv[(size_t)rw * 1536 + c] = f2hbf(v);
                } else {
                    v += bv[c - 1024];
                    int g = rw >> 7, i = rw & 127, hh = (c - 1024) >> 6, d = (c - 1024) & 63;
                    vt[(((size_t)(g * 8 + hh)) * 64 + d) * 128 + i] = f2hbf(v);
                }
            }
        }
}

// ---------------------------------------------------------------------------
// Edge MLP body (chained MFMA, zero LDS, 64 edges/wave), biasE [h][e].
// ---------------------------------------------------------------------------
__device__ __forceinline__ void edge_body(
    int eblk,
    const float* __restrict__ ea,
    const __hip_bfloat16* __restrict__ w1fragt, const float* __restrict__ b1f,
    const __hip_bfloat16* __restrict__ w2at, const float* __restrict__ b2f,
    float* __restrict__ biasE)
{
    int tid = threadIdx.x, wave = tid >> 6, lane = tid & 63;
    int quad = lane >> 4, l16 = lane & 15;
    int eb = eblk * 256 + wave * 64;     // wave owns 64 edges (4 x 16)

    bf16x8 eaf[4] = {};
    if (quad == 0) {
        #pragma unroll
        for (int gg = 0; gg < 4; ++gg) {
            float4 e4 = *(const float4*)(ea + (size_t)(eb + gg * 16 + l16) * 4);
            eaf[gg][0] = f2bf(e4.x); eaf[gg][1] = f2bf(e4.y);
            eaf[gg][2] = f2bf(e4.z); eaf[gg][3] = f2bf(e4.w);
        }
    }

    f32x4 c2[4];
    #pragma unroll
    for (int gg = 0; gg < 4; ++gg)
        #pragma unroll
        for (int r = 0; r < 4; ++r) c2[gg][r] = 0.f;

    #pragma unroll 4
    for (int t = 0; t < 32; ++t) {
        bf16x8 a1 = *(const bf16x8*)(w1fragt + ((size_t)t * 16 + l16) * 8);
        float4 b14 = *(const float4*)(b1f + t * 16 + quad * 4);
        s16x4 a2 = *(const s16x4*)(w2at + ((size_t)t * 64 + lane) * 4);
        #pragma unroll
        for (int gg = 0; gg < 4; ++gg) {
            f32x4 c1 = {0.f, 0.f, 0.f, 0.f};
            c1 = __builtin_amdgcn_mfma_f32_16x16x32_bf16(a1, eaf[gg], c1, 0, 0, 0);
            s16x4 hfrag;
            hfrag[0] = (short)f2u16(fmaxf(c1[0] + b14.x, 0.f));
            hfrag[1] = (short)f2u16(fmaxf(c1[1] + b14.y, 0.f));
            hfrag[2] = (short)f2u16(fmaxf(c1[2] + b14.z, 0.f));
            hfrag[3] = (short)f2u16(fmaxf(c1[3] + b14.w, 0.f));
            c2[gg] = __builtin_amdgcn_mfma_f32_16x16x16bf16_1k(a2, hfrag, c2[gg], 0, 0, 0);
        }
    }
    // c2 lane mapping: head = quad*4+r (quads 0-1), edge = l16.
    if (quad < 2) {
        #pragma unroll
        for (int gg = 0; gg < 4; ++gg) {
            #pragma unroll
            for (int r = 0; r < 4; ++r) {
                int hh = quad * 4 + r;
                biasE[(size_t)hh * E_TOTAL + eb + gg * 16 + l16] = c2[gg][r] + b2f[hh];
            }
        }
    }
}

// ---------------------------------------------------------------------------
// Mega dispatch: blk<768 -> QKV GEMM tile (A = fp32 x); blk>=768 -> edge-MLP.
// ---------------------------------------------------------------------------
__global__ __launch_bounds__(256) void mega_kernel(
    const float* __restrict__ A, const __hip_bfloat16* __restrict__ BT,
    const float* __restrict__ bq, const float* __restrict__ bk,
    const float* __restrict__ bv,
    __hip_bfloat16* __restrict__ qkv, __hip_bfloat16* __restrict__ vt,
    const float* __restrict__ ea,
    const __hip_bfloat16* __restrict__ w1fragt, const float* __restrict__ b1f,
    const __hip_bfloat16* __restrict__ w2at, const float* __restrict__ b2f,
    float* __restrict__ biasE)
{
    __shared__ __align__(16) __hip_bfloat16 As[128 * 32];
    __shared__ __align__(16) __hip_bfloat16 Bs[128 * 32];
    int blk = blockIdx.x;
    if (blk < 768) {
        gemm0_body(A, BT, (blk & 63) * 128, (blk >> 6) * 128,
                   bq, bk, bv, qkv, vt, As, Bs);
    } else {
        edge_body(blk - 768, ea, w1fragt, b1f, w2at, b2f, biasE);
    }
}

// ---------------------------------------------------------------------------
// Out-proj GEMM: 128x64 tiles -> grid (64,8) = 512 blocks = 2/CU.
// Per K-iter: 3 global_load_lds + 8 MFMA. LDS 12 KB.
// ---------------------------------------------------------------------------
__global__ __launch_bounds__(256) void gemm1_kernel(
    const __hip_bfloat16* __restrict__ A, const __hip_bfloat16* __restrict__ BT,
    const float* __restrict__ bo, float* __restrict__ out)
{
    const int K = 512;
    __shared__ __align__(16) __hip_bfloat16 As[128 * 32];   // 8 KB
    __shared__ __align__(16) __hip_bfloat16 Bs[64 * 32];    // 4 KB
    int tid = threadIdx.x;
    int lane = tid & 63, quad = lane >> 4, l16 = lane & 15;
    int wave = tid >> 6, wi = wave >> 1, wj = wave & 1;
    int row0 = blockIdx.x * 128, col0 = blockIdx.y * 64;

    f32x4 acc[4][2];
    #pragma unroll
    for (int a = 0; a < 4; a++)
        #pragma unroll
        for (int b = 0; b < 2; b++)
            #pragma unroll
            for (int r = 0; r < 4; r++) acc[a][b][r] = 0.f;

    const __hip_bfloat16* Ag0 = A + (size_t)(row0 + (tid >> 2)) * K + (tid & 3) * 8;
    const __hip_bfloat16* Ag1 = Ag0 + (size_t)64 * K;
    const __hip_bfloat16* Bg  = BT + (size_t)(col0 + (tid >> 2)) * K + (tid & 3) * 8;
    char* AsB = (char*)As;
    char* BsB = (char*)Bs;

    for (int kt = 0; kt < K / 32; ++kt) {
        __syncthreads();
        __builtin_amdgcn_global_load_lds((glb_char*)(Ag0 + kt * 32), (lds_char*)(AsB + tid * 16), 16, 0, 0);
        __builtin_amdgcn_global_load_lds((glb_char*)(Ag1 + kt * 32), (lds_char*)(AsB + 4096 + tid * 16), 16, 0, 0);
        __builtin_amdgcn_global_load_lds((glb_char*)(Bg + kt * 32), (lds_char*)(BsB + tid * 16), 16, 0, 0);
        __syncthreads();
        bf16x8 af[4], bfr[2];
        #pragma unroll
        for (int t = 0; t < 4; t++)
            af[t] = *(const bf16x8*)&As[(wi * 64 + t * 16 + l16) * 32 + quad * 8];
        #pragma unroll
        for (int t = 0; t < 2; t++)
            bfr[t] = *(const bf16x8*)&Bs[(wj * 32 + t * 16 + l16) * 32 + quad * 8];
        #pragma unroll
        for (int ti = 0; ti < 4; ti++)
            #pragma unroll
            for (int tj = 0; tj < 2; tj++)
                acc[ti][tj] = __builtin_amdgcn_mfma_f32_16x16x32_bf16(af[ti], bfr[tj], acc[ti][tj], 0, 0, 0);
    }

    #pragma unroll
    for (int ti = 0; ti < 4; ti++)
        #pragma unroll
        for (int tj = 0; tj < 2; tj++) {
            int c = col0 + wj * 32 + tj * 16 + l16;
            #pragma unroll
            for (int r = 0; r < 4; r++) {
                int rw = row0 + wi * 64 + ti * 16 + quad * 4 + r;
                out[(size_t)rw * 512 + c] = acc[ti][tj][r] + bo[c];
            }
        }
}

// ---------------------------------------------------------------------------
// Attention (MFMA): one workgroup per (graph, head) — R15-proven version.
// XCD swizzle: g = blk&63, h = blk>>6. S stride 132 floats (<=2-way banks).
// Scatter operands prefetched (coalesced [h][e] biasE) before QK^T.
// ---------------------------------------------------------------------------
#define SS 132
__global__ __launch_bounds__(256) void attn_kernel(
    const __hip_bfloat16* __restrict__ qkv,
    const __hip_bfloat16* __restrict__ vt,
    const float* __restrict__ biasE,
    const int* __restrict__ eidx,
    __hip_bfloat16* __restrict__ O)
{
    __shared__ __align__(16) float S[128 * SS];   // 67584 B
    int blk = blockIdx.x, g = blk & 63, h = blk >> 6;
    int tid = threadIdx.x, wave = tid >> 6, lane = tid & 63;
    int quad = lane >> 4, l16 = lane & 15;

    // ---- prefetch scatter operands (independent of QK^T) into registers
    int   sa[16];   // packed LDS address ls*SS+ld
    float bv[16];
    #pragma unroll
    for (int u = 0; u < 16; ++u) {
        int idx = g * 4096 + tid + u * 256;
        int ls = eidx[idx] & 127;
        int ld = eidx[E_TOTAL + idx] & 127;
        sa[u] = ls * SS + ld;
        bv[u] = biasE[(size_t)h * E_TOTAL + idx];   // coalesced [h][e]
    }

    const __hip_bfloat16* qbase = qkv + (size_t)(g * 128) * 1536 + h * 64;
    const __hip_bfloat16* kbase = qbase + 512;

    // ---- QK^T: wave handles i-tiles {2w,2w+1} x all 8 j-tiles
    f32x4 acc[2][8];
    #pragma unroll
    for (int t = 0; t < 2; t++)
        #pragma unroll
        for (int j = 0; j < 8; j++)
            #pragma unroll
            for (int r = 0; r < 4; r++) acc[t][j][r] = 0.f;

    #pragma unroll
    for (int k0 = 0; k0 < 64; k0 += 32) {
        bf16x8 af[2];
        #pragma unroll
        for (int t = 0; t < 2; t++) {
            int m = wave * 32 + t * 16 + l16;
            af[t] = *(const bf16x8*)(qbase + (size_t)m * 1536 + k0 + quad * 8);
        }
        #pragma unroll
        for (int tj = 0; tj < 8; tj++) {
            int n = tj * 16 + l16;
            bf16x8 bfr = *(const bf16x8*)(kbase + (size_t)n * 1536 + k0 + quad * 8);
            #pragma unroll
            for (int t = 0; t < 2; t++)
                acc[t][tj] = __builtin_amdgcn_mfma_f32_16x16x32_bf16(af[t], bfr, acc[t][tj], 0, 0, 0);
        }
    }
    #pragma unroll
    for (int t = 0; t < 2; t++)
        #pragma unroll
        for (int tj = 0; tj < 8; tj++)
            #pragma unroll
            for (int r = 0; r < 4; r++) {
                int i = wave * 32 + t * 16 + quad * 4 + r;
                int j = tj * 16 + l16;
                S[i * SS + j] = acc[t][tj][r] * 0.125f;   // 1/sqrt(64)
            }
    __syncthreads();

    // ---- edge bias scatter from registers (duplicates accumulate)
    #pragma unroll
    for (int u = 0; u < 16; ++u)
        atomicAdd(&S[sa[u]], bv[u]);
    __syncthreads();

    // ---- softmax over j; wave handles 32 rows; b64 reads, unrolled for ILP
    #pragma unroll 4
    for (int r = wave * 32; r < wave * 32 + 32; ++r) {
        float2 v = *(const float2*)&S[r * SS + 2 * lane];
        float m = fmaxf(v.x, v.y);
        #pragma unroll
        for (int off = 32; off > 0; off >>= 1) m = fmaxf(m, __shfl_xor(m, off));
        float e0 = __expf(v.x - m), e1 = __expf(v.y - m);
        float s = e0 + e1;
        #pragma unroll
        for (int off = 32; off > 0; off >>= 1) s += __shfl_xor(s, off);
        float inv = 1.0f / s;
        float2 o; o.x = e0 * inv; o.y = e1 * inv;
        *(float2*)&S[r * SS + 2 * lane] = o;
    }
    __syncthreads();

    // ---- PV: O(128x64) = P @ V; A-frags are b128 LDS reads, B from vt
    f32x4 oacc[2][4];
    #pragma unroll
    for (int t = 0; t < 2; t++)
        #pragma unroll
        for (int j = 0; j < 4; j++)
            #pragma unroll
            for (int r = 0; r < 4; r++) oacc[t][j][r] = 0.f;

    const __hip_bfloat16* vbase = vt + (size_t)(g * 8 + h) * 64 * 128;
    #pragma unroll
    for (int k0 = 0; k0 < 128; k0 += 32) {
        bf16x8 af[2];
        #pragma unroll
        for (int t = 0; t < 2; t++) {
            int m = wave * 32 + t * 16 + l16;
            const float* p = &S[m * SS + k0 + quad * 8];
            f32x4 xa = *(const f32x4*)p;
            f32x4 xb = *(const f32x4*)(p + 4);
            bf16x8 a;
            a[0] = f2bf(xa[0]); a[1] = f2bf(xa[1]); a[2] = f2bf(xa[2]); a[3] = f2bf(xa[3]);
            a[4] = f2bf(xb[0]); a[5] = f2bf(xb[1]); a[6] = f2bf(xb[2]); a[7] = f2bf(xb[3]);
            af[t] = a;
        }
        #pragma unroll
        for (int tj = 0; tj < 4; tj++) {
            int d = tj * 16 + l16;
            bf16x8 bfr = *(const bf16x8*)(vbase + (size_t)d * 128 + k0 + quad * 8);
            #pragma unroll
            for (int t = 0; t < 2; t++)
                oacc[t][tj] = __builtin_amdgcn_mfma_f32_16x16x32_bf16(af[t], bfr, oacc[t][tj], 0, 0, 0);
        }
    }
    #pragma unroll
    for (int t = 0; t < 2; t++)
        #pragma unroll
        for (int tj = 0; tj < 4; tj++)
            #pragma unroll
            for (int r = 0; r < 4; r++) {
                int i = wave * 32 + t * 16 + quad * 4 + r;
                int d = tj * 16 + l16;
                O[(size_t)(g * 128 + i) * 512 + h * 64 + d] = f2hbf(oacc[t][tj][r]);
            }
}

// ---------------------------------------------------------------------------
// Workspace layout (bytes), total ~53 MB (xb slot retained but unused)
// ---------------------------------------------------------------------------
#define WS_WQKVT 0x0          // 1536*512 bf16 = 1.5 MB
#define WS_WOT   0x180000     // 512*512 bf16 = 0.5 MB
#define WS_W1FR  0x200000     // 512*8 bf16 = 8 KB
#define WS_B1F   0x202000     // 2 KB
#define WS_W2AT  0x202800     // 32*64*4 bf16 = 16 KB
#define WS_B2F   0x206800
#define WS_QKV   0xA10000     // 8192*1536 bf16 = 24 MB
#define WS_VT    0x2210000    // 8 MB
#define WS_BIASE 0x2A10000    // 8*262144 fp32 = 8 MB ([h][e] layout)
#define WS_O     0x3210000    // 8192*512 bf16 = 8 MB

extern "C" void kernel_launch(void* const* d_in, const int* in_sizes, int n_in,
                              void* d_out, int out_size, void* d_ws, size_t ws_size,
                              hipStream_t stream) {
    const float* x    = (const float*)d_in[0];
    const int*   eidx = (const int*)d_in[1];
    const float* ea   = (const float*)d_in[2];
    // d_in[3] = batch, d_in[4] = n_g (unused; block structure is fixed)
    const float* Wq = (const float*)d_in[5];
    const float* bq = (const float*)d_in[6];
    const float* Wk = (const float*)d_in[7];
    const float* bk = (const float*)d_in[8];
    const float* Wv = (const float*)d_in[9];
    const float* bv = (const float*)d_in[10];
    const float* Wo = (const float*)d_in[11];
    const float* bo = (const float*)d_in[12];
    const float* W1 = (const float*)d_in[13];
    const float* b1 = (const float*)d_in[14];
    const float* W2 = (const float*)d_in[15];
    const float* b2 = (const float*)d_in[16];

    char* ws = (char*)d_ws;
    __hip_bfloat16* wqkvt   = (__hip_bfloat16*)(ws + WS_WQKVT);
    __hip_bfloat16* wot     = (__hip_bfloat16*)(ws + WS_WOT);
    __hip_bfloat16* w1fragt = (__hip_bfloat16*)(ws + WS_W1FR);
    float* b1f   = (float*)(ws + WS_B1F);
    __hip_bfloat16* w2at    = (__hip_bfloat16*)(ws + WS_W2AT);
    float* b2f   = (float*)(ws + WS_B2F);
    __hip_bfloat16* qkv = (__hip_bfloat16*)(ws + WS_QKV);
    __hip_bfloat16* vt  = (__hip_bfloat16*)(ws + WS_VT);
    float* biasE = (float*)(ws + WS_BIASE);
    __hip_bfloat16* O   = (__hip_bfloat16*)(ws + WS_O);

    prep_kernel<<<257, 256, 0, stream>>>(Wq, Wk, Wv, Wo, W1, b1, W2, b2,
                                         wqkvt, wot, w1fragt, b1f, w2at, b2f);
    mega_kernel<<<768 + E_TOTAL / 256, 256, 0, stream>>>(
        x, wqkvt, bq, bk, bv, qkv, vt,
        ea, w1fragt, b1f, w2at, b2f, biasE);
    attn_kernel<<<GRAPHS * NHEADS, 256, 0, stream>>>(qkv, vt, biasE, eidx, O);
    gemm1_kernel<<<dim3(NNODES / 128, 512 / 64), 256, 0, stream>>>(
        O, wot, bo, (float*)d_out);
}

// Round 19
// 211.554 us; speedup vs baseline: 1.0171x; 1.0171x over previous
//
#include <hip/hip_runtime.h>
#include <hip/hip_bf16.h>

// Problem constants (fixed by setup_inputs)
#define E_TOTAL 262144
#define NG      128
#define GRAPHS  64
#define NHEADS  8
#define DKH     64
#define DMODEL  512
#define NNODES  8192

typedef __bf16 bf16x8 __attribute__((ext_vector_type(8)));
typedef float  f32x4  __attribute__((ext_vector_type(4)));
typedef short  s16x4  __attribute__((ext_vector_type(4)));
typedef unsigned short u16x8 __attribute__((ext_vector_type(8)));

typedef __attribute__((address_space(3))) char lds_char;
typedef const __attribute__((address_space(1))) char glb_char;

__device__ inline __hip_bfloat16 f2hbf(float f) { return __float2bfloat16(f); }
__device__ inline unsigned short f2u16(float f) {
    return __builtin_bit_cast(unsigned short, __float2bfloat16(f));
}
__device__ inline __bf16 f2bf(float f) {
    return __builtin_bit_cast(__bf16, f2u16(f));
}
__device__ inline bf16x8 cvt8(float4 lo, float4 hi) {
    bf16x8 o;
    o[0] = f2bf(lo.x); o[1] = f2bf(lo.y); o[2] = f2bf(lo.z); o[3] = f2bf(lo.w);
    o[4] = f2bf(hi.x); o[5] = f2bf(hi.y); o[6] = f2bf(hi.z); o[7] = f2bf(hi.w);
    return o;
}

// ---------------------------------------------------------------------------
// Prep: weight transpose/cast + edge-MLP frag tables.
// ---------------------------------------------------------------------------
__global__ __launch_bounds__(256) void prep_kernel(
    const float* __restrict__ Wq, const float* __restrict__ Wk,
    const float* __restrict__ Wv, const float* __restrict__ Wo,
    const float* __restrict__ W1, const float* __restrict__ b1,
    const float* __restrict__ W2, const float* __restrict__ b2,
    __hip_bfloat16* __restrict__ wqkvt, __hip_bfloat16* __restrict__ wot,
    __hip_bfloat16* __restrict__ w1fragt, float* __restrict__ b1f,
    __hip_bfloat16* __restrict__ w2at, float* __restrict__ b2f)
{
    int blk = blockIdx.x, tid = threadIdx.x;
    if (blk < 256) {
        __shared__ __align__(16) __hip_bfloat16 tile[64][65];
        const float* src;
        __hip_bfloat16* dstT;
        int n0, k0, nb;
        if (blk < 192) {
            int nt = blk % 24, ktile = blk / 24;
            n0 = nt * 64; k0 = ktile * 64;
            if (n0 < 512)       { src = Wq; nb = n0; }
            else if (n0 < 1024) { src = Wk; nb = n0 - 512; }
            else                { src = Wv; nb = n0 - 1024; }
            dstT = wqkvt;
        } else {
            int t = blk - 192;
            n0 = (t % 8) * 64; k0 = (t / 8) * 64; nb = n0;
            src = Wo; dstT = wot;
        }
        #pragma unroll
        for (int i = 0; i < 16; ++i) {
            int idx = tid + i * 256;
            int kr = idx >> 6, nc = idx & 63;
            tile[kr][nc] = f2hbf(src[(size_t)(k0 + kr) * 512 + nb + nc]);
        }
        __syncthreads();
        #pragma unroll
        for (int i = 0; i < 16; ++i) {
            int idx = tid + i * 256;
            int nr = idx >> 6, kc = idx & 63;
            dstT[(size_t)(n0 + nr) * 512 + k0 + kc] = tile[kc][nr];
        }
    } else {
        __hip_bfloat16 z = f2hbf(0.f);
        // w1fragt: [512][8]
        for (int n = tid; n < 512; n += 256) {
            #pragma unroll
            for (int j = 0; j < 4; ++j) w1fragt[n * 8 + j] = f2hbf(W1[(size_t)j * 512 + n]);
            #pragma unroll
            for (int j = 4; j < 8; ++j) w1fragt[n * 8 + j] = z;
        }
        for (int i = tid; i < 512; i += 256) b1f[i] = b1[i];
        // w2at: [32][64][4], W2 is (512,8) row-major
        for (int i = tid; i < 32 * 64 * 4; i += 256) {
            int t = i >> 8, lane = (i >> 2) & 63, j = i & 3;
            int q = lane >> 4, l = lane & 15;
            w2at[i] = (l < 8) ? f2hbf(W2[(size_t)(16 * t + 4 * q + j) * 8 + l]) : z;
        }
        if (tid < 8) b2f[tid] = b2[tid];
    }
}

// ---------------------------------------------------------------------------
// QKV GEMM body, 64x128 tile (row-split of R18's 128x128: halves per-block
// acc VGPR and doubles block count for latency cover; A-staging VALU total
// unchanged). A = fp32 x, reg-staged + cvt (1 chunk); B via global_load_lds.
// BK=32. Epilogue: qkv bf16 (Q,K); V only into vt.
// ---------------------------------------------------------------------------
__device__ __forceinline__ void gemm0_body(
    const float* __restrict__ A, const __hip_bfloat16* __restrict__ BT,
    int row0, int col0,
    const float* __restrict__ bq, const float* __restrict__ bk,
    const float* __restrict__ bv,
    __hip_bfloat16* __restrict__ qkv, __hip_bfloat16* __restrict__ vt,
    __hip_bfloat16* As, __hip_bfloat16* Bs)
{
    const int K = 512;
    int tid = threadIdx.x;
    int lane = tid & 63, quad = lane >> 4, l16 = lane & 15;
    int wave = tid >> 6, wi = wave >> 1, wj = wave & 1;

    f32x4 acc[2][4];
    #pragma unroll
    for (int a = 0; a < 2; a++)
        #pragma unroll
        for (int b = 0; b < 4; b++)
            #pragma unroll
            for (int r = 0; r < 4; r++) acc[a][b][r] = 0.f;

    const float* Ag = A + (size_t)(row0 + (tid >> 2)) * K + (tid & 3) * 8;
    const __hip_bfloat16* Bg0 = BT + (size_t)(col0 + (tid >> 2)) * K + (tid & 3) * 8;
    const __hip_bfloat16* Bg1 = Bg0 + (size_t)64 * K;
    char* BsB = (char*)Bs;
    int lidx = tid * 8;

    for (int kt = 0; kt < K / 32; ++kt) {
        // prefetch A (fp32) into registers before the barrier
        float4 a0l = *(const float4*)(Ag + kt * 32);
        float4 a0h = *(const float4*)(Ag + kt * 32 + 4);
        __syncthreads();   // prior iteration's frag reads complete
        __builtin_amdgcn_global_load_lds((glb_char*)(Bg0 + kt * 32), (lds_char*)(BsB + tid * 16), 16, 0, 0);
        __builtin_amdgcn_global_load_lds((glb_char*)(Bg1 + kt * 32), (lds_char*)(BsB + 4096 + tid * 16), 16, 0, 0);
        *(bf16x8*)&As[lidx] = cvt8(a0l, a0h);
        __syncthreads();   // staging visible (compiler drains vmcnt here)
        bf16x8 af[2], bfr[4];
        #pragma unroll
        for (int t = 0; t < 2; t++)
            af[t] = *(const bf16x8*)&As[(wi * 32 + t * 16 + l16) * 32 + quad * 8];
        #pragma unroll
        for (int t = 0; t < 4; t++)
            bfr[t] = *(const bf16x8*)&Bs[(wj * 64 + t * 16 + l16) * 32 + quad * 8];
        #pragma unroll
        for (int ti = 0; ti < 2; ti++)
            #pragma unroll
            for (int tj = 0; tj < 4; tj++)
                acc[ti][tj] = __builtin_amdgcn_mfma_f32_16x16x32_bf16(af[ti], bfr[tj], acc[ti][tj], 0, 0, 0);
    }

    #pragma unroll
    for (int ti = 0; ti < 2; ti++)
        #pragma unroll
        for (int tj = 0; tj < 4; tj++) {
            int c = col0 + wj * 64 + tj * 16 + l16;
            #pragma unroll
            for (int r = 0; r < 4; r++) {
                int rw = row0 + wi * 32 + ti * 16 + quad * 4 + r;
                float v = acc[ti][tj][r];
                if (c < 1024) {
                    v += (c < 512) ? bq[c] : bk[c - 512];
                    qkv[(size_t)rw * 1536 + c] = f2hbf(v);
                } else {
                    v += bv[c - 1024];
                    int g = rw >> 7, i = rw & 127, hh = (c - 1024) >> 6, d = (c - 1024) & 63;
                    vt[(((size_t)(g * 8 + hh)) * 64 + d) * 128 + i] = f2hbf(v);
                }
            }
        }
}

// ---------------------------------------------------------------------------
// Edge MLP body (chained MFMA, zero LDS, 64 edges/wave), biasE [h][e].
// ---------------------------------------------------------------------------
__device__ __forceinline__ void edge_body(
    int eblk,
    const float* __restrict__ ea,
    const __hip_bfloat16* __restrict__ w1fragt, const float* __restrict__ b1f,
    const __hip_bfloat16* __restrict__ w2at, const float* __restrict__ b2f,
    float* __restrict__ biasE)
{
    int tid = threadIdx.x, wave = tid >> 6, lane = tid & 63;
    int quad = lane >> 4, l16 = lane & 15;
    int eb = eblk * 256 + wave * 64;     // wave owns 64 edges (4 x 16)

    bf16x8 eaf[4] = {};
    if (quad == 0) {
        #pragma unroll
        for (int gg = 0; gg < 4; ++gg) {
            float4 e4 = *(const float4*)(ea + (size_t)(eb + gg * 16 + l16) * 4);
            eaf[gg][0] = f2bf(e4.x); eaf[gg][1] = f2bf(e4.y);
            eaf[gg][2] = f2bf(e4.z); eaf[gg][3] = f2bf(e4.w);
        }
    }

    f32x4 c2[4];
    #pragma unroll
    for (int gg = 0; gg < 4; ++gg)
        #pragma unroll
        for (int r = 0; r < 4; ++r) c2[gg][r] = 0.f;

    #pragma unroll 4
    for (int t = 0; t < 32; ++t) {
        bf16x8 a1 = *(const bf16x8*)(w1fragt + ((size_t)t * 16 + l16) * 8);
        float4 b14 = *(const float4*)(b1f + t * 16 + quad * 4);
        s16x4 a2 = *(const s16x4*)(w2at + ((size_t)t * 64 + lane) * 4);
        #pragma unroll
        for (int gg = 0; gg < 4; ++gg) {
            f32x4 c1 = {0.f, 0.f, 0.f, 0.f};
            c1 = __builtin_amdgcn_mfma_f32_16x16x32_bf16(a1, eaf[gg], c1, 0, 0, 0);
            s16x4 hfrag;
            hfrag[0] = (short)f2u16(fmaxf(c1[0] + b14.x, 0.f));
            hfrag[1] = (short)f2u16(fmaxf(c1[1] + b14.y, 0.f));
            hfrag[2] = (short)f2u16(fmaxf(c1[2] + b14.z, 0.f));
            hfrag[3] = (short)f2u16(fmaxf(c1[3] + b14.w, 0.f));
            c2[gg] = __builtin_amdgcn_mfma_f32_16x16x16bf16_1k(a2, hfrag, c2[gg], 0, 0, 0);
        }
    }
    // c2 lane mapping: head = quad*4+r (quads 0-1), edge = l16.
    if (quad < 2) {
        #pragma unroll
        for (int gg = 0; gg < 4; ++gg) {
            #pragma unroll
            for (int r = 0; r < 4; ++r) {
                int hh = quad * 4 + r;
                biasE[(size_t)hh * E_TOTAL + eb + gg * 16 + l16] = c2[gg][r] + b2f[hh];
            }
        }
    }
}

// ---------------------------------------------------------------------------
// Mega dispatch: blk<1536 -> 64x128 QKV GEMM tile (row = blk&127, col-tile =
// blk>>7; consecutive blocks share the B tile for L2 reuse); blk>=1536 ->
// edge-MLP block.
// ---------------------------------------------------------------------------
__global__ __launch_bounds__(256) void mega_kernel(
    const float* __restrict__ A, const __hip_bfloat16* __restrict__ BT,
    const float* __restrict__ bq, const float* __restrict__ bk,
    const float* __restrict__ bv,
    __hip_bfloat16* __restrict__ qkv, __hip_bfloat16* __restrict__ vt,
    const float* __restrict__ ea,
    const __hip_bfloat16* __restrict__ w1fragt, const float* __restrict__ b1f,
    const __hip_bfloat16* __restrict__ w2at, const float* __restrict__ b2f,
    float* __restrict__ biasE)
{
    __shared__ __align__(16) __hip_bfloat16 As[64 * 32];    // 4 KB
    __shared__ __align__(16) __hip_bfloat16 Bs[128 * 32];   // 8 KB
    int blk = blockIdx.x;
    if (blk < 1536) {
        gemm0_body(A, BT, (blk & 127) * 64, (blk >> 7) * 128,
                   bq, bk, bv, qkv, vt, As, Bs);
    } else {
        edge_body(blk - 1536, ea, w1fragt, b1f, w2at, b2f, biasE);
    }
}

// ---------------------------------------------------------------------------
// Out-proj GEMM: 128x64 tiles -> grid (64,8) = 512 blocks = 2/CU.
// ---------------------------------------------------------------------------
__global__ __launch_bounds__(256) void gemm1_kernel(
    const __hip_bfloat16* __restrict__ A, const __hip_bfloat16* __restrict__ BT,
    const float* __restrict__ bo, float* __restrict__ out)
{
    const int K = 512;
    __shared__ __align__(16) __hip_bfloat16 As[128 * 32];   // 8 KB
    __shared__ __align__(16) __hip_bfloat16 Bs[64 * 32];    // 4 KB
    int tid = threadIdx.x;
    int lane = tid & 63, quad = lane >> 4, l16 = lane & 15;
    int wave = tid >> 6, wi = wave >> 1, wj = wave & 1;
    int row0 = blockIdx.x * 128, col0 = blockIdx.y * 64;

    f32x4 acc[4][2];
    #pragma unroll
    for (int a = 0; a < 4; a++)
        #pragma unroll
        for (int b = 0; b < 2; b++)
            #pragma unroll
            for (int r = 0; r < 4; r++) acc[a][b][r] = 0.f;

    const __hip_bfloat16* Ag0 = A + (size_t)(row0 + (tid >> 2)) * K + (tid & 3) * 8;
    const __hip_bfloat16* Ag1 = Ag0 + (size_t)64 * K;
    const __hip_bfloat16* Bg  = BT + (size_t)(col0 + (tid >> 2)) * K + (tid & 3) * 8;
    char* AsB = (char*)As;
    char* BsB = (char*)Bs;

    for (int kt = 0; kt < K / 32; ++kt) {
        __syncthreads();
        __builtin_amdgcn_global_load_lds((glb_char*)(Ag0 + kt * 32), (lds_char*)(AsB + tid * 16), 16, 0, 0);
        __builtin_amdgcn_global_load_lds((glb_char*)(Ag1 + kt * 32), (lds_char*)(AsB + 4096 + tid * 16), 16, 0, 0);
        __builtin_amdgcn_global_load_lds((glb_char*)(Bg + kt * 32), (lds_char*)(BsB + tid * 16), 16, 0, 0);
        __syncthreads();
        bf16x8 af[4], bfr[2];
        #pragma unroll
        for (int t = 0; t < 4; t++)
            af[t] = *(const bf16x8*)&As[(wi * 64 + t * 16 + l16) * 32 + quad * 8];
        #pragma unroll
        for (int t = 0; t < 2; t++)
            bfr[t] = *(const bf16x8*)&Bs[(wj * 32 + t * 16 + l16) * 32 + quad * 8];
        #pragma unroll
        for (int ti = 0; ti < 4; ti++)
            #pragma unroll
            for (int tj = 0; tj < 2; tj++)
                acc[ti][tj] = __builtin_amdgcn_mfma_f32_16x16x32_bf16(af[ti], bfr[tj], acc[ti][tj], 0, 0, 0);
    }

    #pragma unroll
    for (int ti = 0; ti < 4; ti++)
        #pragma unroll
        for (int tj = 0; tj < 2; tj++) {
            int c = col0 + wj * 32 + tj * 16 + l16;
            #pragma unroll
            for (int r = 0; r < 4; r++) {
                int rw = row0 + wi * 64 + ti * 16 + quad * 4 + r;
                out[(size_t)rw * 512 + c] = acc[ti][tj][r] + bo[c];
            }
        }
}

// ---------------------------------------------------------------------------
// Attention (MFMA): one workgroup per (graph, head) — R15-proven version.
// XCD swizzle: g = blk&63, h = blk>>6. S stride 132 floats (<=2-way banks).
// Scatter operands prefetched (coalesced [h][e] biasE) before QK^T.
// ---------------------------------------------------------------------------
#define SS 132
__global__ __launch_bounds__(256) void attn_kernel(
    const __hip_bfloat16* __restrict__ qkv,
    const __hip_bfloat16* __restrict__ vt,
    const float* __restrict__ biasE,
    const int* __restrict__ eidx,
    __hip_bfloat16* __restrict__ O)
{
    __shared__ __align__(16) float S[128 * SS];   // 67584 B
    int blk = blockIdx.x, g = blk & 63, h = blk >> 6;
    int tid = threadIdx.x, wave = tid >> 6, lane = tid & 63;
    int quad = lane >> 4, l16 = lane & 15;

    // ---- prefetch scatter operands (independent of QK^T) into registers
    int   sa[16];   // packed LDS address ls*SS+ld
    float bv[16];
    #pragma unroll
    for (int u = 0; u < 16; ++u) {
        int idx = g * 4096 + tid + u * 256;
        int ls = eidx[idx] & 127;
        int ld = eidx[E_TOTAL + idx] & 127;
        sa[u] = ls * SS + ld;
        bv[u] = biasE[(size_t)h * E_TOTAL + idx];   // coalesced [h][e]
    }

    const __hip_bfloat16* qbase = qkv + (size_t)(g * 128) * 1536 + h * 64;
    const __hip_bfloat16* kbase = qbase + 512;

    // ---- QK^T: wave handles i-tiles {2w,2w+1} x all 8 j-tiles
    f32x4 acc[2][8];
    #pragma unroll
    for (int t = 0; t < 2; t++)
        #pragma unroll
        for (int j = 0; j < 8; j++)
            #pragma unroll
            for (int r = 0; r < 4; r++) acc[t][j][r] = 0.f;

    #pragma unroll
    for (int k0 = 0; k0 < 64; k0 += 32) {
        bf16x8 af[2];
        #pragma unroll
        for (int t = 0; t < 2; t++) {
            int m = wave * 32 + t * 16 + l16;
            af[t] = *(const bf16x8*)(qbase + (size_t)m * 1536 + k0 + quad * 8);
        }
        #pragma unroll
        for (int tj = 0; tj < 8; tj++) {
            int n = tj * 16 + l16;
            bf16x8 bfr = *(const bf16x8*)(kbase + (size_t)n * 1536 + k0 + quad * 8);
            #pragma unroll
            for (int t = 0; t < 2; t++)
                acc[t][tj] = __builtin_amdgcn_mfma_f32_16x16x32_bf16(af[t], bfr, acc[t][tj], 0, 0, 0);
        }
    }
    #pragma unroll
    for (int t = 0; t < 2; t++)
        #pragma unroll
        for (int tj = 0; tj < 8; tj++)
            #pragma unroll
            for (int r = 0; r < 4; r++) {
                int i = wave * 32 + t * 16 + quad * 4 + r;
                int j = tj * 16 + l16;
                S[i * SS + j] = acc[t][tj][r] * 0.125f;   // 1/sqrt(64)
            }
    __syncthreads();

    // ---- edge bias scatter from registers (duplicates accumulate)
    #pragma unroll
    for (int u = 0; u < 16; ++u)
        atomicAdd(&S[sa[u]], bv[u]);
    __syncthreads();

    // ---- softmax over j; wave handles 32 rows; b64 reads, unrolled for ILP
    #pragma unroll 4
    for (int r = wave * 32; r < wave * 32 + 32; ++r) {
        float2 v = *(const float2*)&S[r * SS + 2 * lane];
        float m = fmaxf(v.x, v.y);
        #pragma unroll
        for (int off = 32; off > 0; off >>= 1) m = fmaxf(m, __shfl_xor(m, off));
        float e0 = __expf(v.x - m), e1 = __expf(v.y - m);
        float s = e0 + e1;
        #pragma unroll
        for (int off = 32; off > 0; off >>= 1) s += __shfl_xor(s, off);
        float inv = 1.0f / s;
        float2 o; o.x = e0 * inv; o.y = e1 * inv;
        *(float2*)&S[r * SS + 2 * lane] = o;
    }
    __syncthreads();

    // ---- PV: O(128x64) = P @ V; A-frags are b128 LDS reads, B from vt
    f32x4 oacc[2][4];
    #pragma unroll
    for (int t = 0; t < 2; t++)
        #pragma unroll
        for (int j = 0; j < 4; j++)
            #pragma unroll
            for (int r = 0; r < 4; r++) oacc[t][j][r] = 0.f;

    const __hip_bfloat16* vbase = vt + (size_t)(g * 8 + h) * 64 * 128;
    #pragma unroll
    for (int k0 = 0; k0 < 128; k0 += 32) {
        bf16x8 af[2];
        #pragma unroll
        for (int t = 0; t < 2; t++) {
            int m = wave * 32 + t * 16 + l16;
            const float* p = &S[m * SS + k0 + quad * 8];
            f32x4 xa = *(const f32x4*)p;
            f32x4 xb = *(const f32x4*)(p + 4);
            bf16x8 a;
            a[0] = f2bf(xa[0]); a[1] = f2bf(xa[1]); a[2] = f2bf(xa[2]); a[3] = f2bf(xa[3]);
            a[4] = f2bf(xb[0]); a[5] = f2bf(xb[1]); a[6] = f2bf(xb[2]); a[7] = f2bf(xb[3]);
            af[t] = a;
        }
        #pragma unroll
        for (int tj = 0; tj < 4; tj++) {
            int d = tj * 16 + l16;
            bf16x8 bfr = *(const bf16x8*)(vbase + (size_t)d * 128 + k0 + quad * 8);
            #pragma unroll
            for (int t = 0; t < 2; t++)
                oacc[t][tj] = __builtin_amdgcn_mfma_f32_16x16x32_bf16(af[t], bfr, oacc[t][tj], 0, 0, 0);
        }
    }
    #pragma unroll
    for (int t = 0; t < 2; t++)
        #pragma unroll
        for (int tj = 0; tj < 4; tj++)
            #pragma unroll
            for (int r = 0; r < 4; r++) {
                int i = wave * 32 + t * 16 + quad * 4 + r;
                int d = tj * 16 + l16;
                O[(size_t)(g * 128 + i) * 512 + h * 64 + d] = f2hbf(oacc[t][tj][r]);
            }
}

// ---------------------------------------------------------------------------
// Workspace layout (bytes), total ~53 MB
// ---------------------------------------------------------------------------
#define WS_WQKVT 0x0          // 1536*512 bf16 = 1.5 MB
#define WS_WOT   0x180000     // 512*512 bf16 = 0.5 MB
#define WS_W1FR  0x200000     // 512*8 bf16 = 8 KB
#define WS_B1F   0x202000     // 2 KB
#define WS_W2AT  0x202800     // 32*64*4 bf16 = 16 KB
#define WS_B2F   0x206800
#define WS_QKV   0xA10000     // 8192*1536 bf16 = 24 MB
#define WS_VT    0x2210000    // 8 MB
#define WS_BIASE 0x2A10000    // 8*262144 fp32 = 8 MB ([h][e] layout)
#define WS_O     0x3210000    // 8192*512 bf16 = 8 MB

extern "C" void kernel_launch(void* const* d_in, const int* in_sizes, int n_in,
                              void* d_out, int out_size, void* d_ws, size_t ws_size,
                              hipStream_t stream) {
    const float* x    = (const float*)d_in[0];
    const int*   eidx = (const int*)d_in[1];
    const float* ea   = (const float*)d_in[2];
    // d_in[3] = batch, d_in[4] = n_g (unused; block structure is fixed)
    const float* Wq = (const float*)d_in[5];
    const float* bq = (const float*)d_in[6];
    const float* Wk = (const float*)d_in[7];
    const float* bk = (const float*)d_in[8];
    const float* Wv = (const float*)d_in[9];
    const float* bv = (const float*)d_in[10];
    const float* Wo = (const float*)d_in[11];
    const float* bo = (const float*)d_in[12];
    const float* W1 = (const float*)d_in[13];
    const float* b1 = (const float*)d_in[14];
    const float* W2 = (const float*)d_in[15];
    const float* b2 = (const float*)d_in[16];

    char* ws = (char*)d_ws;
    __hip_bfloat16* wqkvt   = (__hip_bfloat16*)(ws + WS_WQKVT);
    __hip_bfloat16* wot     = (__hip_bfloat16*)(ws + WS_WOT);
    __hip_bfloat16* w1fragt = (__hip_bfloat16*)(ws + WS_W1FR);
    float* b1f   = (float*)(ws + WS_B1F);
    __hip_bfloat16* w2at    = (__hip_bfloat16*)(ws + WS_W2AT);
    float* b2f   = (float*)(ws + WS_B2F);
    __hip_bfloat16* qkv = (__hip_bfloat16*)(ws + WS_QKV);
    __hip_bfloat16* vt  = (__hip_bfloat16*)(ws + WS_VT);
    float* biasE = (float*)(ws + WS_BIASE);
    __hip_bfloat16* O   = (__hip_bfloat16*)(ws + WS_O);

    prep_kernel<<<257, 256, 0, stream>>>(Wq, Wk, Wv, Wo, W1, b1, W2, b2,
                                         wqkvt, wot, w1fragt, b1f, w2at, b2f);
    mega_kernel<<<1536 + E_TOTAL / 256, 256, 0, stream>>>(
        x, wqkvt, bq, bk, bv, qkv, vt,
        ea, w1fragt, b1f, w2at, b2f, biasE);
    attn_kernel<<<GRAPHS * NHEADS, 256, 0, stream>>>(qkv, vt, biasE, eidx, O);
    gemm1_kernel<<<dim3(NNODES / 128, 512 / 64), 256, 0, stream>>>(
        O, wot, bo, (float*)d_out);
}